// Round 4
// baseline (356.371 us; speedup 1.0000x reference)
//
#include <hip/hip_runtime.h>
#include <stdint.h>
#include <stddef.h>

// ---------- problem constants ----------
constexpr int BATCH = 2;
constexpr int SEQ   = 2048;
constexpr int EMB   = 2048;   // DIM
constexpr int HEADS = 16;
constexpr int GQA   = 4;      // kv heads
constexpr int HDIM  = 128;
constexpr int NQKV  = 3072;   // 2048 Q + 512 K + 512 V
constexpr int VOFF  = 2560;   // column offset of V region in fused QKV
constexpr int MROWS = BATCH * SEQ;  // 4096

typedef _Float16 half8  __attribute__((ext_vector_type(8)));
typedef _Float16 half4v __attribute__((ext_vector_type(4)));
typedef float    floatx4 __attribute__((ext_vector_type(4)));

__device__ __forceinline__ void st_c(float* p, float v)    { *p = v; }
__device__ __forceinline__ void st_c(_Float16* p, float v) { *p = (_Float16)v; }

// async global->LDS, 16 B per lane, LDS dest = wave-uniform base + lane*16
__device__ __forceinline__ void gld16(const _Float16* g, _Float16* l) {
    __builtin_amdgcn_global_load_lds(
        (const __attribute__((address_space(1))) void*)g,
        (__attribute__((address_space(3))) void*)l, 16, 0, 0);
}

// counted vmcnt wait (compile-time immediate)
template <int N>
__device__ __forceinline__ void waitvm() {
    if constexpr (N == 8)      asm volatile("s_waitcnt vmcnt(8)" ::: "memory");
    else if constexpr (N == 6) asm volatile("s_waitcnt vmcnt(6)" ::: "memory");
    else if constexpr (N == 4) asm volatile("s_waitcnt vmcnt(4)" ::: "memory");
    else if constexpr (N == 3) asm volatile("s_waitcnt vmcnt(3)" ::: "memory");
    else                       asm volatile("s_waitcnt vmcnt(0)" ::: "memory");
}

// ---------- 1. cast x (fp32 -> f16) ----------
__global__ void cast_x_kernel(const float* __restrict__ x, _Float16* __restrict__ xh) {
    int i = (blockIdx.x * 256 + threadIdx.x) * 4;
    float4 v = *(const float4*)(x + i);
    half4v h;
    h[0] = (_Float16)v.x; h[1] = (_Float16)v.y; h[2] = (_Float16)v.z; h[3] = (_Float16)v.w;
    *(half4v*)(xh + i) = h;
}

// ---------- 2. transpose + cast: out[C x R] = in[R x C]^T ----------
__global__ void transpose_cast(const float* __restrict__ in, _Float16* __restrict__ out,
                               int R, int C) {
    __shared__ float tile[32][33];
    int cb = blockIdx.x * 32, rb = blockIdx.y * 32;
    int tx = threadIdx.x, ty = threadIdx.y;    // 32 x 8
    #pragma unroll
    for (int j = 0; j < 32; j += 8)
        tile[ty + j][tx] = in[(size_t)(rb + ty + j) * C + (cb + tx)];
    __syncthreads();
    #pragma unroll
    for (int j = 0; j < 32; j += 8)
        out[(size_t)(cb + ty + j) * R + (rb + tx)] = (_Float16)tile[tx][ty + j];
}

// ---------- 3. GEMM: C[M,N] = A[M,K] * Bt[N,K]^T  (f16 in, fp32 acc) ----------
// 256-class multi-phase structure (T2+T3+T4+T5), plain-HIP derivation:
//  - BK=64 split into two kk-phases; LDS regions keyed (slot, kk); dbuf slots.
//  - Staging of region R is issued only in the phase AFTER R's last reader
//    phase has barriered -> async DMA can never land into a live region.
//    Schedule: P(t,1): stage (t+1).k1 -> slot(t^1).k1 (last read P(t-1,2));
//              P(t,2): stage (t+2).k0 -> slot(t).k0  (last read P(t,1)).
//  - Counted vmcnt: 3 groups in flight, wait to 2*GROUP (never 0 mid-loop);
//    issue->need lead = 3 phases (~900 cyc) covers HBM-miss latency.
//  - XOR chunk swizzle BOTH sides (rule #21): per-lane inverse-swizzled
//    global source for gld16 (LDS stays linear) + swizzled ds_read address.
//    key(r) = (r>>1)&3 on the 16B-chunk index; fragment reads become 2-way
//    (free) instead of 8..16-way bank-conflicted at 64B row stride.
//  - Per-wave tile (BM/2)x(BN/4): MFMA:ds_read = 64:24 at 256x256.
//  - setprio(1) around the MFMA cluster (T5: pays once phase-split exists).
// GROUP = gld16s per stage-group per thread = BM/128 + BN/128.
template <int BM, int BN, int MF, int NF, typename CT, bool ROPE>
__global__ __launch_bounds__(512, 2) void gemm_8p(const _Float16* __restrict__ A,
                                                  const _Float16* __restrict__ Bt,
                                                  CT* __restrict__ C,
                                                  int M, int N, int K,
                                                  const float* __restrict__ fc,
                                                  const float* __restrict__ fs) {
    constexpr int GROUP = BM / 128 + BN / 128;
    __shared__ _Float16 As[4 * BM * 32];   // [slot*2+kk][BM rows][32 f16]
    __shared__ _Float16 Bs[4 * BN * 32];
    const int tid  = threadIdx.x;          // 512 threads = 8 waves
    const int bm   = blockIdx.y * BM, bn = blockIdx.x * BN;
    const int lane = tid & 63, wid = tid >> 6;
    const int wr   = wid >> 2, wc = wid & 3;          // 2M x 4N wave grid
    const int qd   = lane >> 4, m15 = lane & 15;

    // staging: one gld16 covers 16 rows x 32 f16 (1 KB). Wave wid owns rows
    // [wid*16,+16) (and [128+wid*16,+16) when the tile has 256 rows).
    // lane l -> dest row wid*16 + (l>>2), dest chunk (l&3); source chunk is
    // pre-swizzled: (l&3) ^ key(row) with key(row)=(row>>1)&3 = (l>>3)&3.
    const int srow   = lane >> 2;
    const int schunk = (lane & 3) ^ ((lane >> 3) & 3);
    const _Float16* Ag = A  + (size_t)(bm + wid * 16 + srow) * K + schunk * 8;
    const _Float16* Bg = Bt + (size_t)(bn + wid * 16 + srow) * K + schunk * 8;

    floatx4 acc[MF][NF] = {};

    auto STAGE = [&](int tt, int kk, int ss) {
        const int koff = tt * 64 + kk * 32;
        _Float16* aw = As + (ss * 2 + kk) * (BM * 32) + wid * 16 * 32;
        gld16(Ag + koff, aw);
        if constexpr (BM == 256) gld16(Ag + (size_t)128 * K + koff, aw + 128 * 32);
        _Float16* bw = Bs + (ss * 2 + kk) * (BN * 32) + wid * 16 * 32;
        gld16(Bg + koff, bw);
        if constexpr (BN == 256) gld16(Bg + (size_t)128 * K + koff, bw + 128 * 32);
    };

    // read-side swizzled chunk offset: rows here are == 0 mod 16 at the frag
    // base, so key(row) = (m15>>1)&3 for every fragment.
    const int rsw = (qd ^ ((m15 >> 1) & 3)) * 8;

    auto COMPUTE = [&](int ss, int kk) {
        const _Float16* ab = As + (ss * 2 + kk) * (BM * 32);
        const _Float16* bb = Bs + (ss * 2 + kk) * (BN * 32);
        half8 bf[NF], af[MF];
        #pragma unroll
        for (int i = 0; i < NF; i++)
            bf[i] = *(const half8*)(bb + (wc * (BN / 4) + i * 16 + m15) * 32 + rsw);
        #pragma unroll
        for (int i = 0; i < MF; i++)
            af[i] = *(const half8*)(ab + (wr * (BM / 2) + i * 16 + m15) * 32 + rsw);
        __builtin_amdgcn_s_setprio(1);
        #pragma unroll
        for (int mi = 0; mi < MF; mi++)
            #pragma unroll
            for (int ni = 0; ni < NF; ni++)
                acc[mi][ni] = __builtin_amdgcn_mfma_f32_16x16x32_f16(af[mi], bf[ni], acc[mi][ni], 0, 0, 0);
        __builtin_amdgcn_s_setprio(0);
    };

    const int nt = K >> 6;   // K-tiles of 64 (nt >= 2 for this schedule)
    // prologue: groups (0,k0) (0,k1) (1,k0) -> 3 groups in flight
    STAGE(0, 0, 0);
    STAGE(0, 1, 0);
    STAGE(1, 0, 1);

    for (int t = 0; t < nt; ++t) {
        const int s = t & 1;
        // ---- phase 1: compute kk=0 of tile t ----
        if (t + 1 < nt) waitvm<2 * GROUP>();   // retire (t).k0; keep 2 groups in flight
        else            waitvm<GROUP>();
        __builtin_amdgcn_s_barrier();          // (t).k0 visible to all; prev readers done
        if (t + 1 < nt) STAGE(t + 1, 1, s ^ 1);   // -> slot(s^1).k1, last read P(t-1,2)
        COMPUTE(s, 0);
        __builtin_amdgcn_s_barrier();
        // ---- phase 2: compute kk=1 of tile t ----
        if (t + 1 < nt) waitvm<2 * GROUP>();   // retire (t).k1
        else            waitvm<0>();
        __builtin_amdgcn_s_barrier();
        if (t + 2 < nt) STAGE(t + 2, 0, s);       // -> slot(s).k0, last read P(t,1)
        COMPUTE(s, 1);
        __builtin_amdgcn_s_barrier();
    }

    #pragma unroll
    for (int mi = 0; mi < MF; mi++)
        #pragma unroll
        for (int ni = 0; ni < NF; ni++)
            #pragma unroll
            for (int r = 0; r < 4; r++) {
                int row = bm + wr * (BM / 2) + mi * 16 + qd * 4 + r;
                int col = bn + wc * (BN / 4) + ni * 16 + m15;
                float v = acc[mi][ni][r];
                if (ROPE && col < VOFF) {
                    int si = row & (SEQ - 1);
                    int fi = (col >> 1) & 63;
                    float c  = fc[si * 64 + fi];
                    float sn = fs[si * 64 + fi];
                    float other = __shfl_xor(v, 1, 64);
                    v = (m15 & 1) ? (v * c + other * sn) : (v * c - other * sn);
                }
                st_c(&C[(size_t)row * N + col], v);
            }
}

// ---------- 4b. V -> Vt[b][g][d][s]  (d rows 0..127) ----------
__global__ void transpose_v(const _Float16* __restrict__ qkv, _Float16* __restrict__ vt) {
    __shared__ _Float16 tile[32][33];
    int sb = blockIdx.x * 32, db = blockIdx.y * 32;
    int bg = blockIdx.z;
    int tx = threadIdx.x, ty = threadIdx.y;
    const _Float16* src = qkv + (size_t)(bg >> 2) * SEQ * NQKV + VOFF + (bg & 3) * HDIM;
    #pragma unroll
    for (int j = 0; j < 32; j += 8)
        tile[ty + j][tx] = src[(size_t)(sb + ty + j) * NQKV + db + tx];
    __syncthreads();
    _Float16* dst = vt + (size_t)bg * HDIM * SEQ;
    #pragma unroll
    for (int j = 0; j < 32; j += 8)
        dst[(size_t)(db + ty + j) * SEQ + sb + tx] = tile[tx][ty + j];
}

// ---------- 5. flash attention: 8 waves (4 heads x 2 row-halves), paired q-tiles ----------
// (unchanged; verified in prior rounds)
__global__ __launch_bounds__(512, 2) void flash_attn(const _Float16* __restrict__ qkv,
                                                     const _Float16* __restrict__ vt,
                                                     _Float16* __restrict__ ob) {
    const int bx   = blockIdx.x;   // 0..31
    const int g    = blockIdx.y;
    const int b    = blockIdx.z;
    const int tid  = threadIdx.x;
    const int lane = tid & 63, wid = tid >> 6;   // 8 waves
    const int h    = g * 4 + (wid & 3);
    const int su   = wid >> 2;                   // which 16-row half of the 32-row tile
    const int qd   = lane >> 4, m15 = lane & 15;

    __shared__ _Float16 Ks[2][64 * 128];   // [key][d], swizzled 16B chunks
    __shared__ _Float16 Vs[2][128 * 64];   // [d][key], swizzled
    __shared__ _Float16 Ps[8][16 * 64];    // per-wave P slice, swizzled

    const _Float16* kg = qkv + (size_t)(b * SEQ) * NQKV + EMB + g * HDIM;
    const _Float16* vg = vt + (size_t)(b * GQA + g) * HDIM * SEQ;
    _Float16* pw = Ps[wid];

    const int kl = lane >> 4, kc16 = lane & 15;
    const int vl = lane >> 3, vc8  = lane & 7;
    const _Float16* kgp[2]; const _Float16* vgp[2];
    int ksoff[2], vsoff[2];
    #pragma unroll
    for (int j = 0; j < 2; j++) {
        int t = wid * 2 + j;
        int kr = t * 4 + kl;
        kgp[j] = kg + (size_t)kr * NQKV + ((kc16 ^ (kr & 15)) * 8);
        ksoff[j] = t * 512;
        int vr = t * 8 + vl;
        vgp[j] = vg + (size_t)vr * SEQ + ((vc8 ^ (vr & 7)) * 8);
        vsoff[j] = t * 512;
    }

    half8 ones;
    #pragma unroll
    for (int i = 0; i < 8; i++) ones[i] = (_Float16)1.0f;
    const _Float16 qsc = (_Float16)(0.08838834764831845f * 1.44269504088896341f);

    for (int ph = 0; ph < 2; ++ph) {
        const int sidx   = ph ? bx : 63 - bx;
        const int q0     = sidx * 32;
        const int ktLast = sidx >> 1;

        __syncthreads();
        #pragma unroll
        for (int j = 0; j < 2; j++) gld16(kgp[j], &Ks[0][ksoff[j]]);
        #pragma unroll
        for (int j = 0; j < 2; j++) gld16(vgp[j], &Vs[0][vsoff[j]]);

        half8 qf[4];
        {
            const _Float16* qb = qkv + (size_t)(b * SEQ + q0 + su * 16 + m15) * NQKV + h * HDIM + qd * 8;
            #pragma unroll
            for (int kc = 0; kc < 4; kc++) {
                half8 q = *(const half8*)(qb + kc * 32);
                #pragma unroll
                for (int i = 0; i < 8; i++) q[i] = (_Float16)(q[i] * qsc);
                qf[kc] = q;
            }
        }

        floatx4 o[9] = {};   // [0..7]=dims, [8]=denominator

        for (int kt = 0; kt <= ktLast; ++kt) {
            const int cur = kt & 1;
            __syncthreads();
            if (kt < ktLast) {
                const int nb = cur ^ 1;
                const size_t ko = (size_t)(kt + 1) * 64;
                #pragma unroll
                for (int j = 0; j < 2; j++) gld16(kgp[j] + ko * NQKV, &Ks[nb][ksoff[j]]);
                #pragma unroll
                for (int j = 0; j < 2; j++) gld16(vgp[j] + ko, &Vs[nb][vsoff[j]]);
            }
            const _Float16* ksb = Ks[cur];
            const _Float16* vsb = Vs[cur];

            floatx4 sa[4] = {};
            __builtin_amdgcn_s_setprio(1);
            #pragma unroll
            for (int nt = 0; nt < 4; ++nt) {
                const int kr = nt * 16 + m15;
                #pragma unroll
                for (int kc = 0; kc < 4; ++kc) {
                    half8 kf = *(const half8*)(&ksb[kr * 128 + (((kc * 4 + qd) ^ (kr & 15)) * 8)]);
                    sa[nt] = __builtin_amdgcn_mfma_f32_16x16x32_f16(qf[kc], kf, sa[nt], 0, 0, 0);
                }
            }
            __builtin_amdgcn_s_setprio(0);

            const bool diag = (kt == ktLast);
            const int  k0   = kt * 64;
            #pragma unroll
            for (int r = 0; r < 4; r++) {
                const int prow = qd * 4 + r;
                const int rowg = q0 + su * 16 + prow;
                #pragma unroll
                for (int nt = 0; nt < 4; nt++) {
                    float p = __builtin_exp2f(sa[nt][r]);
                    if (diag && (k0 + nt * 16 + m15 > rowg)) p = 0.f;
                    int chunk = (nt * 2 + (m15 >> 3)) ^ (prow & 7);
                    pw[prow * 64 + chunk * 8 + (m15 & 7)] = (_Float16)p;
                }
            }

            half8 pf[2];
            #pragma unroll
            for (int kc = 0; kc < 2; kc++)
                pf[kc] = *(const half8*)(&pw[m15 * 64 + (((kc * 4 + qd) ^ (m15 & 7)) * 8)]);

            __builtin_amdgcn_s_setprio(1);
            #pragma unroll
            for (int dt = 0; dt < 8; dt++) {
                const int vr = dt * 16 + m15;
                #pragma unroll
                for (int kc = 0; kc < 2; kc++) {
                    half8 vf = *(const half8*)(&vsb[vr * 64 + (((kc * 4 + qd) ^ (vr & 7)) * 8)]);
                    o[dt] = __builtin_amdgcn_mfma_f32_16x16x32_f16(pf[kc], vf, o[dt], 0, 0, 0);
                }
            }
            o[8] = __builtin_amdgcn_mfma_f32_16x16x32_f16(pf[0], ones, o[8], 0, 0, 0);
            o[8] = __builtin_amdgcn_mfma_f32_16x16x32_f16(pf[1], ones, o[8], 0, 0, 0);
            __builtin_amdgcn_s_setprio(0);
        }

        float linv[4];
        #pragma unroll
        for (int r = 0; r < 4; r++) linv[r] = 1.0f / o[8][r];
        _Float16* od = ob + (size_t)(b * SEQ + q0 + su * 16) * EMB + h * HDIM;
        #pragma unroll
        for (int dt = 0; dt < 8; dt++)
            #pragma unroll
            for (int r = 0; r < 4; r++)
                od[(size_t)(qd * 4 + r) * EMB + dt * 16 + m15] = (_Float16)(o[dt][r] * linv[r]);
    }
}

// ---------- launcher ----------
extern "C" void kernel_launch(void* const* d_in, const int* in_sizes, int n_in,
                              void* d_out, int out_size, void* d_ws, size_t ws_size,
                              hipStream_t stream) {
    (void)in_sizes; (void)n_in; (void)out_size; (void)ws_size;
    const float* x  = (const float*)d_in[0];
    const float* fc = (const float*)d_in[1];
    const float* fs = (const float*)d_in[2];
    const float* Wq = (const float*)d_in[3];
    const float* Wk = (const float*)d_in[4];
    const float* Wv = (const float*)d_in[5];
    const float* Wo = (const float*)d_in[6];
    float* out = (float*)d_out;

    // workspace layout (f16), 60 MB
    _Float16* Xb   = (_Float16*)d_ws;
    _Float16* Wqkv = Xb   + (size_t)MROWS * EMB;
    _Float16* WoT  = Wqkv + (size_t)NQKV * EMB;
    _Float16* C1   = WoT  + (size_t)EMB * EMB;
    _Float16* Vt   = Wqkv;                         // reuse (after QKV GEMM)
    _Float16* Ob   = Xb;                           // reuse (after QKV GEMM)

    dim3 tb(32, 8);
    cast_x_kernel<<<MROWS * EMB / 1024, 256, 0, stream>>>(x, Xb);
    transpose_cast<<<dim3(EMB / 32, EMB / 32), tb, 0, stream>>>(Wq, Wqkv, EMB, EMB);
    transpose_cast<<<dim3(512 / 32, EMB / 32), tb, 0, stream>>>(Wk, Wqkv + (size_t)EMB * EMB, EMB, 512);
    transpose_cast<<<dim3(512 / 32, EMB / 32), tb, 0, stream>>>(Wv, Wqkv + (size_t)VOFF * EMB, EMB, 512);
    transpose_cast<<<dim3(EMB / 32, EMB / 32), tb, 0, stream>>>(Wo, WoT, EMB, EMB);

    // QKV: 256x256 tile, grid 12x16=192 blocks (75% CU fill, best FLOP/ds_read)
    gemm_8p<256, 256, 8, 4, _Float16, true><<<dim3(NQKV / 256, MROWS / 256), 512, 0, stream>>>(
        Xb, Wqkv, C1, MROWS, NQKV, EMB, fc, fs);
    transpose_v<<<dim3(SEQ / 32, HDIM / 32, BATCH * GQA), tb, 0, stream>>>(C1, Vt);
    flash_attn<<<dim3(32, GQA, BATCH), 512, 0, stream>>>(C1, Vt, Ob);
    // out-proj: 128x256 tile, grid 8x32=256 blocks (100% CU fill)
    gemm_8p<128, 256, 4, 4, float, false><<<dim3(EMB / 256, MROWS / 128), 512, 0, stream>>>(
        Ob, WoT, out, MROWS, EMB, EMB, nullptr, nullptr);
}

// Round 5
// 328.061 us; speedup vs baseline: 1.0863x; 1.0863x over previous
//
#include <hip/hip_runtime.h>
#include <stdint.h>
#include <stddef.h>

// ---------- problem constants ----------
constexpr int BATCH = 2;
constexpr int SEQ   = 2048;
constexpr int EMB   = 2048;   // DIM
constexpr int HEADS = 16;
constexpr int GQA   = 4;      // kv heads
constexpr int HDIM  = 128;
constexpr int NQKV  = 3072;   // 2048 Q + 512 K + 512 V
constexpr int VOFF  = 2560;   // column offset of V region in fused QKV
constexpr int MROWS = BATCH * SEQ;  // 4096

typedef _Float16 half8  __attribute__((ext_vector_type(8)));
typedef _Float16 half4v __attribute__((ext_vector_type(4)));
typedef float    floatx4 __attribute__((ext_vector_type(4)));

__device__ __forceinline__ void st_c(float* p, float v)    { *p = v; }
__device__ __forceinline__ void st_c(_Float16* p, float v) { *p = (_Float16)v; }

// async global->LDS, 16 B per lane, LDS dest = wave-uniform base + lane*16
__device__ __forceinline__ void gld16(const _Float16* g, _Float16* l) {
    __builtin_amdgcn_global_load_lds(
        (const __attribute__((address_space(1))) void*)g,
        (__attribute__((address_space(3))) void*)l, 16, 0, 0);
}

// ---------- 1. cast x (fp32 -> f16) ----------
__global__ void cast_x_kernel(const float* __restrict__ x, _Float16* __restrict__ xh) {
    int i = (blockIdx.x * 256 + threadIdx.x) * 4;
    float4 v = *(const float4*)(x + i);
    half4v h;
    h[0] = (_Float16)v.x; h[1] = (_Float16)v.y; h[2] = (_Float16)v.z; h[3] = (_Float16)v.w;
    *(half4v*)(xh + i) = h;
}

// ---------- 2. transpose + cast: out[C x R] = in[R x C]^T ----------
__global__ void transpose_cast(const float* __restrict__ in, _Float16* __restrict__ out,
                               int R, int C) {
    __shared__ float tile[32][33];
    int cb = blockIdx.x * 32, rb = blockIdx.y * 32;
    int tx = threadIdx.x, ty = threadIdx.y;    // 32 x 8
    #pragma unroll
    for (int j = 0; j < 32; j += 8)
        tile[ty + j][tx] = in[(size_t)(rb + ty + j) * C + (cb + tx)];
    __syncthreads();
    #pragma unroll
    for (int j = 0; j < 32; j += 8)
        out[(size_t)(cb + ty + j) * R + (rb + tx)] = (_Float16)tile[tx][ty + j];
}

// ============================================================================
// Fine-phase GEMM (m201-class): 4 phases per K-tile of 64, each phase
// {ds_read quadrant frags; stage 8KB unit(s); barrier; setprio; MFMA; setprio;
// barrier}. Quadrant order (M0,N0)(M0,N1)(M1,N1)(M1,N0); bf01 register-
// retained A->D so B-LDS regions die after phase B, A-regions after C.
// Staging units (64 rows x 64 f16 = 8KB = 1 gld16/thread, uniform per wave)
// go only to dead regions: other-slot at A/B, current-slot B-units at C/D.
// One counted vmcnt per K-tile (in-flight = C+D stage units), never 0
// mid-loop; min prefetch lead = 2 phases. XOR 16B-chunk swizzle both sides
// (inverse-swizzled global src for the linear gld16 dest + swizzled ds_read):
// rows are 128B so chunk' = chunk ^ (row&7) spreads the 16-lane column walk
// across all banks (2-way = free).
// ============================================================================

// ---------- 3a. QKV GEMM: BM=256 x BN=192, 8 waves (2M x 4N), per-wave 128x48
__global__ __launch_bounds__(512, 2) void gemm_qkv(const _Float16* __restrict__ A,
                                                   const _Float16* __restrict__ Bt,
                                                   _Float16* __restrict__ C,
                                                   int M, int N, int K,
                                                   const float* __restrict__ fc,
                                                   const float* __restrict__ fs) {
    constexpr int BM = 256, BN = 192;
    __shared__ _Float16 As[2][BM * 64];
    __shared__ _Float16 Bs[2][BN * 64];
    const int tid  = threadIdx.x;
    const int bm   = blockIdx.y * BM, bn = blockIdx.x * BN;
    const int lane = tid & 63, wid = tid >> 6;
    const int wr   = wid >> 2, wc = wid & 3;
    const int qd   = lane >> 4, m15 = lane & 15;
    const int l8   = lane >> 3, c8 = lane & 7;
    const int schunk = c8 ^ (l8 & 7);                 // inverse read-swizzle

    const _Float16* Ag = A  + (size_t)(bm + wid * 8 + l8) * K + schunk * 8;
    const _Float16* Bg = Bt + (size_t)(bn + wid * 8 + l8) * K + schunk * 8;
    _Float16* AsW = &As[0][0] + wid * 8 * 64;
    _Float16* BsW = &Bs[0][0] + wid * 8 * 64;

    auto stA = [&](int s, int R0, int k) { gld16(Ag + (size_t)R0 * K + k, AsW + s * (BM * 64) + R0 * 64); };
    auto stB = [&](int s, int R0, int k) { gld16(Bg + (size_t)R0 * K + k, BsW + s * (BN * 64) + R0 * 64); };

    floatx4 acc[8][3] = {};
    const int nt = K >> 6;                 // 32 K-tiles of 64
    const int rswz = m15 & 7;

    // prologue: tile0 all 7 units + tile1 b-units (3) -> 10 in flight
    stA(0, 0, 0); stA(0, 64, 0); stA(0, 128, 0); stA(0, 192, 0);
    stB(0, 0, 0); stB(0, 64, 0); stB(0, 128, 0);
    stB(1, 0, 64); stB(1, 64, 64); stB(1, 128, 64);
    asm volatile("s_waitcnt vmcnt(3)" ::: "memory");   // tile0 resident; tile1 b's in flight
    __builtin_amdgcn_s_barrier();

    for (int u = 0; u < nt; ++u) {
        const int s  = u & 1;
        const int kn = (u + 1) * 64, kn2 = (u + 2) * 64;
        const _Float16* Ab = &As[s][0];
        const _Float16* Bb = &Bs[s][0];
        half8 af[4][2], bf01[2][2], bf2[2];

        // ---- phase A: (M0,N0) ----
        #pragma unroll
        for (int mi = 0; mi < 4; mi++)
            #pragma unroll
            for (int k2 = 0; k2 < 2; k2++)
                af[mi][k2] = *(const half8*)(Ab + (wr * 128 + mi * 16 + m15) * 64 + (((k2 * 4 + qd) ^ rswz) * 8));
        #pragma unroll
        for (int ni = 0; ni < 2; ni++)
            #pragma unroll
            for (int k2 = 0; k2 < 2; k2++)
                bf01[ni][k2] = *(const half8*)(Bb + (wc * 48 + ni * 16 + m15) * 64 + (((k2 * 4 + qd) ^ rswz) * 8));
        if (u + 1 < nt) { stA(s ^ 1, 0, kn); stA(s ^ 1, 128, kn); }
        __builtin_amdgcn_s_barrier();
        __builtin_amdgcn_s_setprio(1);
        #pragma unroll
        for (int mi = 0; mi < 4; mi++)
            #pragma unroll
            for (int ni = 0; ni < 2; ni++)
                #pragma unroll
                for (int k2 = 0; k2 < 2; k2++)
                    acc[mi][ni] = __builtin_amdgcn_mfma_f32_16x16x32_f16(af[mi][k2], bf01[ni][k2], acc[mi][ni], 0, 0, 0);
        __builtin_amdgcn_s_setprio(0);
        __builtin_amdgcn_s_barrier();

        // ---- phase B: (M0,n2) ----
        #pragma unroll
        for (int k2 = 0; k2 < 2; k2++)
            bf2[k2] = *(const half8*)(Bb + (wc * 48 + 2 * 16 + m15) * 64 + (((k2 * 4 + qd) ^ rswz) * 8));
        if (u + 1 < nt) { stA(s ^ 1, 64, kn); stA(s ^ 1, 192, kn); }
        __builtin_amdgcn_s_barrier();
        __builtin_amdgcn_s_setprio(1);
        #pragma unroll
        for (int mi = 0; mi < 4; mi++)
            #pragma unroll
            for (int k2 = 0; k2 < 2; k2++)
                acc[mi][2] = __builtin_amdgcn_mfma_f32_16x16x32_f16(af[mi][k2], bf2[k2], acc[mi][2], 0, 0, 0);
        __builtin_amdgcn_s_setprio(0);
        __builtin_amdgcn_s_barrier();

        // ---- phase C: (M1,n2) ----
        #pragma unroll
        for (int mi = 0; mi < 4; mi++)
            #pragma unroll
            for (int k2 = 0; k2 < 2; k2++)
                af[mi][k2] = *(const half8*)(Ab + (wr * 128 + 64 + mi * 16 + m15) * 64 + (((k2 * 4 + qd) ^ rswz) * 8));
        if (u + 2 < nt) { stB(s, 0, kn2); stB(s, 64, kn2); }   // current-slot B dead since B
        __builtin_amdgcn_s_barrier();
        __builtin_amdgcn_s_setprio(1);
        #pragma unroll
        for (int mi = 0; mi < 4; mi++)
            #pragma unroll
            for (int k2 = 0; k2 < 2; k2++)
                acc[4 + mi][2] = __builtin_amdgcn_mfma_f32_16x16x32_f16(af[mi][k2], bf2[k2], acc[4 + mi][2], 0, 0, 0);
        __builtin_amdgcn_s_setprio(0);
        __builtin_amdgcn_s_barrier();

        // ---- phase D: (M1,N0) ----
        if (u + 2 < nt) stB(s, 128, kn2);
        if (u + 2 < nt)      { asm volatile("s_waitcnt vmcnt(3)" ::: "memory"); }  // tile u+1 resident
        else if (u + 1 < nt) { asm volatile("s_waitcnt vmcnt(0)" ::: "memory"); }
        __builtin_amdgcn_s_barrier();
        __builtin_amdgcn_s_setprio(1);
        #pragma unroll
        for (int mi = 0; mi < 4; mi++)
            #pragma unroll
            for (int ni = 0; ni < 2; ni++)
                #pragma unroll
                for (int k2 = 0; k2 < 2; k2++)
                    acc[4 + mi][ni] = __builtin_amdgcn_mfma_f32_16x16x32_f16(af[mi][k2], bf01[ni][k2], acc[4 + mi][ni], 0, 0, 0);
        __builtin_amdgcn_s_setprio(0);
        __builtin_amdgcn_s_barrier();
    }

    // epilogue with fused RoPE
    #pragma unroll
    for (int ai = 0; ai < 8; ai++)
        #pragma unroll
        for (int ni = 0; ni < 3; ni++)
            #pragma unroll
            for (int r = 0; r < 4; r++) {
                int row = bm + wr * 128 + ai * 16 + qd * 4 + r;
                int col = bn + wc * 48 + ni * 16 + m15;
                float v = acc[ai][ni][r];
                if (col < VOFF) {
                    int si = row & (SEQ - 1);
                    int fi = (col >> 1) & 63;
                    float c  = fc[si * 64 + fi];
                    float sn = fs[si * 64 + fi];
                    float other = __shfl_xor(v, 1, 64);
                    v = (m15 & 1) ? (v * c + other * sn) : (v * c - other * sn);
                }
                C[(size_t)row * N + col] = (_Float16)v;
            }
}

// ---------- 3b. out-proj GEMM: BM=128 x BN=256, 8 waves (2M x 4N), per-wave 64x64
__global__ __launch_bounds__(512, 2) void gemm_out(const _Float16* __restrict__ A,
                                                   const _Float16* __restrict__ Bt,
                                                   float* __restrict__ C,
                                                   int M, int N, int K) {
    constexpr int BM = 128, BN = 256;
    __shared__ _Float16 As[2][BM * 64];
    __shared__ _Float16 Bs[2][BN * 64];
    const int tid  = threadIdx.x;
    const int bm   = blockIdx.y * BM, bn = blockIdx.x * BN;
    const int lane = tid & 63, wid = tid >> 6;
    const int wr   = wid >> 2, wc = wid & 3;
    const int qd   = lane >> 4, m15 = lane & 15;
    const int l8   = lane >> 3, c8 = lane & 7;
    const int schunk = c8 ^ (l8 & 7);

    const _Float16* Ag = A  + (size_t)(bm + wid * 8 + l8) * K + schunk * 8;
    const _Float16* Bg = Bt + (size_t)(bn + wid * 8 + l8) * K + schunk * 8;
    _Float16* AsW = &As[0][0] + wid * 8 * 64;
    _Float16* BsW = &Bs[0][0] + wid * 8 * 64;

    auto stA = [&](int s, int R0, int k) { gld16(Ag + (size_t)R0 * K + k, AsW + s * (BM * 64) + R0 * 64); };
    auto stB = [&](int s, int R0, int k) { gld16(Bg + (size_t)R0 * K + k, BsW + s * (BN * 64) + R0 * 64); };

    floatx4 acc[4][4] = {};
    const int nt = K >> 6;
    const int rswz = m15 & 7;

    // prologue: tile0 6 units + tile1 {b2,b3}
    stA(0, 0, 0); stA(0, 64, 0);
    stB(0, 0, 0); stB(0, 64, 0); stB(0, 128, 0); stB(0, 192, 0);
    stB(1, 128, 64); stB(1, 192, 64);
    asm volatile("s_waitcnt vmcnt(2)" ::: "memory");
    __builtin_amdgcn_s_barrier();

    for (int u = 0; u < nt; ++u) {
        const int s  = u & 1;
        const int kn = (u + 1) * 64, kn2 = (u + 2) * 64;
        const _Float16* Ab = &As[s][0];
        const _Float16* Bb = &Bs[s][0];
        half8 af[2][2], bf01[2][2], bf23[2][2];

        // ---- phase A: (M0,N0) ----
        #pragma unroll
        for (int mi = 0; mi < 2; mi++)
            #pragma unroll
            for (int k2 = 0; k2 < 2; k2++)
                af[mi][k2] = *(const half8*)(Ab + (wr * 64 + mi * 16 + m15) * 64 + (((k2 * 4 + qd) ^ rswz) * 8));
        #pragma unroll
        for (int ni = 0; ni < 2; ni++)
            #pragma unroll
            for (int k2 = 0; k2 < 2; k2++)
                bf01[ni][k2] = *(const half8*)(Bb + (wc * 64 + ni * 16 + m15) * 64 + (((k2 * 4 + qd) ^ rswz) * 8));
        if (u + 1 < nt) { stA(s ^ 1, 0, kn); stA(s ^ 1, 64, kn); }
        __builtin_amdgcn_s_barrier();
        __builtin_amdgcn_s_setprio(1);
        #pragma unroll
        for (int mi = 0; mi < 2; mi++)
            #pragma unroll
            for (int ni = 0; ni < 2; ni++)
                #pragma unroll
                for (int k2 = 0; k2 < 2; k2++)
                    acc[mi][ni] = __builtin_amdgcn_mfma_f32_16x16x32_f16(af[mi][k2], bf01[ni][k2], acc[mi][ni], 0, 0, 0);
        __builtin_amdgcn_s_setprio(0);
        __builtin_amdgcn_s_barrier();

        // ---- phase B: (M0,N1) ----
        #pragma unroll
        for (int ni = 0; ni < 2; ni++)
            #pragma unroll
            for (int k2 = 0; k2 < 2; k2++)
                bf23[ni][k2] = *(const half8*)(Bb + (wc * 64 + (2 + ni) * 16 + m15) * 64 + (((k2 * 4 + qd) ^ rswz) * 8));
        if (u + 1 < nt) { stB(s ^ 1, 0, kn); stB(s ^ 1, 64, kn); }
        __builtin_amdgcn_s_barrier();
        __builtin_amdgcn_s_setprio(1);
        #pragma unroll
        for (int mi = 0; mi < 2; mi++)
            #pragma unroll
            for (int ni = 0; ni < 2; ni++)
                #pragma unroll
                for (int k2 = 0; k2 < 2; k2++)
                    acc[mi][2 + ni] = __builtin_amdgcn_mfma_f32_16x16x32_f16(af[mi][k2], bf23[ni][k2], acc[mi][2 + ni], 0, 0, 0);
        __builtin_amdgcn_s_setprio(0);
        __builtin_amdgcn_s_barrier();

        // ---- phase C: (M1,N1) ----
        #pragma unroll
        for (int mi = 0; mi < 2; mi++)
            #pragma unroll
            for (int k2 = 0; k2 < 2; k2++)
                af[mi][k2] = *(const half8*)(Ab + (wr * 64 + 32 + mi * 16 + m15) * 64 + (((k2 * 4 + qd) ^ rswz) * 8));
        if (u + 2 < nt) stB(s, 128, kn2);                 // current-slot B dead since B
        __builtin_amdgcn_s_barrier();
        __builtin_amdgcn_s_setprio(1);
        #pragma unroll
        for (int mi = 0; mi < 2; mi++)
            #pragma unroll
            for (int ni = 0; ni < 2; ni++)
                #pragma unroll
                for (int k2 = 0; k2 < 2; k2++)
                    acc[2 + mi][2 + ni] = __builtin_amdgcn_mfma_f32_16x16x32_f16(af[mi][k2], bf23[ni][k2], acc[2 + mi][2 + ni], 0, 0, 0);
        __builtin_amdgcn_s_setprio(0);
        __builtin_amdgcn_s_barrier();

        // ---- phase D: (M1,N0) ----
        if (u + 2 < nt) stB(s, 192, kn2);
        if (u + 2 < nt)      { asm volatile("s_waitcnt vmcnt(2)" ::: "memory"); }
        else if (u + 1 < nt) { asm volatile("s_waitcnt vmcnt(0)" ::: "memory"); }
        __builtin_amdgcn_s_barrier();
        __builtin_amdgcn_s_setprio(1);
        #pragma unroll
        for (int mi = 0; mi < 2; mi++)
            #pragma unroll
            for (int ni = 0; ni < 2; ni++)
                #pragma unroll
                for (int k2 = 0; k2 < 2; k2++)
                    acc[2 + mi][ni] = __builtin_amdgcn_mfma_f32_16x16x32_f16(af[mi][k2], bf01[ni][k2], acc[2 + mi][ni], 0, 0, 0);
        __builtin_amdgcn_s_setprio(0);
        __builtin_amdgcn_s_barrier();
    }

    #pragma unroll
    for (int ai = 0; ai < 4; ai++)
        #pragma unroll
        for (int ni = 0; ni < 4; ni++)
            #pragma unroll
            for (int r = 0; r < 4; r++) {
                int row = bm + wr * 64 + ai * 16 + qd * 4 + r;
                int col = bn + wc * 64 + ni * 16 + m15;
                C[(size_t)row * N + col] = acc[ai][ni][r];
            }
}

// ---------- 4b. V -> Vt[b][g][d][s]  (d rows 0..127) ----------
__global__ void transpose_v(const _Float16* __restrict__ qkv, _Float16* __restrict__ vt) {
    __shared__ _Float16 tile[32][33];
    int sb = blockIdx.x * 32, db = blockIdx.y * 32;
    int bg = blockIdx.z;
    int tx = threadIdx.x, ty = threadIdx.y;
    const _Float16* src = qkv + (size_t)(bg >> 2) * SEQ * NQKV + VOFF + (bg & 3) * HDIM;
    #pragma unroll
    for (int j = 0; j < 32; j += 8)
        tile[ty + j][tx] = src[(size_t)(sb + ty + j) * NQKV + db + tx];
    __syncthreads();
    _Float16* dst = vt + (size_t)bg * HDIM * SEQ;
    #pragma unroll
    for (int j = 0; j < 32; j += 8)
        dst[(size_t)(db + ty + j) * SEQ + sb + tx] = tile[tx][ty + j];
}

// ---------- 5. flash attention (unchanged, verified) ----------
__global__ __launch_bounds__(512, 2) void flash_attn(const _Float16* __restrict__ qkv,
                                                     const _Float16* __restrict__ vt,
                                                     _Float16* __restrict__ ob) {
    const int bx   = blockIdx.x;   // 0..31
    const int g    = blockIdx.y;
    const int b    = blockIdx.z;
    const int tid  = threadIdx.x;
    const int lane = tid & 63, wid = tid >> 6;   // 8 waves
    const int h    = g * 4 + (wid & 3);
    const int su   = wid >> 2;
    const int qd   = lane >> 4, m15 = lane & 15;

    __shared__ _Float16 Ks[2][64 * 128];
    __shared__ _Float16 Vs[2][128 * 64];
    __shared__ _Float16 Ps[8][16 * 64];

    const _Float16* kg = qkv + (size_t)(b * SEQ) * NQKV + EMB + g * HDIM;
    const _Float16* vg = vt + (size_t)(b * GQA + g) * HDIM * SEQ;
    _Float16* pw = Ps[wid];

    const int kl = lane >> 4, kc16 = lane & 15;
    const int vl = lane >> 3, vc8  = lane & 7;
    const _Float16* kgp[2]; const _Float16* vgp[2];
    int ksoff[2], vsoff[2];
    #pragma unroll
    for (int j = 0; j < 2; j++) {
        int t = wid * 2 + j;
        int kr = t * 4 + kl;
        kgp[j] = kg + (size_t)kr * NQKV + ((kc16 ^ (kr & 15)) * 8);
        ksoff[j] = t * 512;
        int vr = t * 8 + vl;
        vgp[j] = vg + (size_t)vr * SEQ + ((vc8 ^ (vr & 7)) * 8);
        vsoff[j] = t * 512;
    }

    half8 ones;
    #pragma unroll
    for (int i = 0; i < 8; i++) ones[i] = (_Float16)1.0f;
    const _Float16 qsc = (_Float16)(0.08838834764831845f * 1.44269504088896341f);

    for (int ph = 0; ph < 2; ++ph) {
        const int sidx   = ph ? bx : 63 - bx;
        const int q0     = sidx * 32;
        const int ktLast = sidx >> 1;

        __syncthreads();
        #pragma unroll
        for (int j = 0; j < 2; j++) gld16(kgp[j], &Ks[0][ksoff[j]]);
        #pragma unroll
        for (int j = 0; j < 2; j++) gld16(vgp[j], &Vs[0][vsoff[j]]);

        half8 qf[4];
        {
            const _Float16* qb = qkv + (size_t)(b * SEQ + q0 + su * 16 + m15) * NQKV + h * HDIM + qd * 8;
            #pragma unroll
            for (int kc = 0; kc < 4; kc++) {
                half8 q = *(const half8*)(qb + kc * 32);
                #pragma unroll
                for (int i = 0; i < 8; i++) q[i] = (_Float16)(q[i] * qsc);
                qf[kc] = q;
            }
        }

        floatx4 o[9] = {};

        for (int kt = 0; kt <= ktLast; ++kt) {
            const int cur = kt & 1;
            __syncthreads();
            if (kt < ktLast) {
                const int nb = cur ^ 1;
                const size_t ko = (size_t)(kt + 1) * 64;
                #pragma unroll
                for (int j = 0; j < 2; j++) gld16(kgp[j] + ko * NQKV, &Ks[nb][ksoff[j]]);
                #pragma unroll
                for (int j = 0; j < 2; j++) gld16(vgp[j] + ko, &Vs[nb][vsoff[j]]);
            }
            const _Float16* ksb = Ks[cur];
            const _Float16* vsb = Vs[cur];

            floatx4 sa[4] = {};
            __builtin_amdgcn_s_setprio(1);
            #pragma unroll
            for (int nt = 0; nt < 4; ++nt) {
                const int kr = nt * 16 + m15;
                #pragma unroll
                for (int kc = 0; kc < 4; ++kc) {
                    half8 kf = *(const half8*)(&ksb[kr * 128 + (((kc * 4 + qd) ^ (kr & 15)) * 8)]);
                    sa[nt] = __builtin_amdgcn_mfma_f32_16x16x32_f16(qf[kc], kf, sa[nt], 0, 0, 0);
                }
            }
            __builtin_amdgcn_s_setprio(0);

            const bool diag = (kt == ktLast);
            const int  k0   = kt * 64;
            #pragma unroll
            for (int r = 0; r < 4; r++) {
                const int prow = qd * 4 + r;
                const int rowg = q0 + su * 16 + prow;
                #pragma unroll
                for (int nt = 0; nt < 4; nt++) {
                    float p = __builtin_exp2f(sa[nt][r]);
                    if (diag && (k0 + nt * 16 + m15 > rowg)) p = 0.f;
                    int chunk = (nt * 2 + (m15 >> 3)) ^ (prow & 7);
                    pw[prow * 64 + chunk * 8 + (m15 & 7)] = (_Float16)p;
                }
            }

            half8 pf[2];
            #pragma unroll
            for (int kc = 0; kc < 2; kc++)
                pf[kc] = *(const half8*)(&pw[m15 * 64 + (((kc * 4 + qd) ^ (m15 & 7)) * 8)]);

            __builtin_amdgcn_s_setprio(1);
            #pragma unroll
            for (int dt = 0; dt < 8; dt++) {
                const int vr = dt * 16 + m15;
                #pragma unroll
                for (int kc = 0; kc < 2; kc++) {
                    half8 vf = *(const half8*)(&vsb[vr * 64 + (((kc * 4 + qd) ^ (vr & 7)) * 8)]);
                    o[dt] = __builtin_amdgcn_mfma_f32_16x16x32_f16(pf[kc], vf, o[dt], 0, 0, 0);
                }
            }
            o[8] = __builtin_amdgcn_mfma_f32_16x16x32_f16(pf[0], ones, o[8], 0, 0, 0);
            o[8] = __builtin_amdgcn_mfma_f32_16x16x32_f16(pf[1], ones, o[8], 0, 0, 0);
            __builtin_amdgcn_s_setprio(0);
        }

        float linv[4];
        #pragma unroll
        for (int r = 0; r < 4; r++) linv[r] = 1.0f / o[8][r];
        _Float16* od = ob + (size_t)(b * SEQ + q0 + su * 16) * EMB + h * HDIM;
        #pragma unroll
        for (int dt = 0; dt < 8; dt++)
            #pragma unroll
            for (int r = 0; r < 4; r++)
                od[(size_t)(qd * 4 + r) * EMB + dt * 16 + m15] = (_Float16)(o[dt][r] * linv[r]);
    }
}

// ---------- launcher ----------
extern "C" void kernel_launch(void* const* d_in, const int* in_sizes, int n_in,
                              void* d_out, int out_size, void* d_ws, size_t ws_size,
                              hipStream_t stream) {
    (void)in_sizes; (void)n_in; (void)out_size; (void)ws_size;
    const float* x  = (const float*)d_in[0];
    const float* fc = (const float*)d_in[1];
    const float* fs = (const float*)d_in[2];
    const float* Wq = (const float*)d_in[3];
    const float* Wk = (const float*)d_in[4];
    const float* Wv = (const float*)d_in[5];
    const float* Wo = (const float*)d_in[6];
    float* out = (float*)d_out;

    // workspace layout (f16), 60 MB
    _Float16* Xb   = (_Float16*)d_ws;
    _Float16* Wqkv = Xb   + (size_t)MROWS * EMB;
    _Float16* WoT  = Wqkv + (size_t)NQKV * EMB;
    _Float16* C1   = WoT  + (size_t)EMB * EMB;
    _Float16* Vt   = Wqkv;                         // reuse (after QKV GEMM)
    _Float16* Ob   = Xb;                           // reuse (after QKV GEMM)

    dim3 tb(32, 8);
    cast_x_kernel<<<MROWS * EMB / 1024, 256, 0, stream>>>(x, Xb);
    transpose_cast<<<dim3(EMB / 32, EMB / 32), tb, 0, stream>>>(Wq, Wqkv, EMB, EMB);
    transpose_cast<<<dim3(512 / 32, EMB / 32), tb, 0, stream>>>(Wk, Wqkv + (size_t)EMB * EMB, EMB, 512);
    transpose_cast<<<dim3(512 / 32, EMB / 32), tb, 0, stream>>>(Wv, Wqkv + (size_t)VOFF * EMB, EMB, 512);
    transpose_cast<<<dim3(EMB / 32, EMB / 32), tb, 0, stream>>>(Wo, WoT, EMB, EMB);

    // QKV: 256x192 tile -> grid 16x16 = 256 blocks (100% CU fill)
    gemm_qkv<<<dim3(NQKV / 192, MROWS / 256), 512, 0, stream>>>(
        Xb, Wqkv, C1, MROWS, NQKV, EMB, fc, fs);
    transpose_v<<<dim3(SEQ / 32, HDIM / 32, BATCH * GQA), tb, 0, stream>>>(C1, Vt);
    flash_attn<<<dim3(32, GQA, BATCH), 512, 0, stream>>>(C1, Vt, Ob);
    // out-proj: 128x256 tile -> grid 8x32 = 256 blocks (100% CU fill)
    gemm_out<<<dim3(EMB / 256, MROWS / 128), 512, 0, stream>>>(
        Ob, WoT, out, MROWS, EMB, EMB);
}

// Round 6
// 317.071 us; speedup vs baseline: 1.1239x; 1.0347x over previous
//
#include <hip/hip_runtime.h>
#include <stdint.h>
#include <stddef.h>

// ---------- problem constants ----------
constexpr int BATCH = 2;
constexpr int SEQ   = 2048;
constexpr int EMB   = 2048;   // DIM
constexpr int HEADS = 16;
constexpr int GQA   = 4;      // kv heads
constexpr int HDIM  = 128;
constexpr int NQKV  = 3072;   // 2048 Q + 512 K + 512 V
constexpr int VOFF  = 2560;   // column offset of V region in fused QKV
constexpr int MROWS = BATCH * SEQ;  // 4096

typedef _Float16 half8  __attribute__((ext_vector_type(8)));
typedef _Float16 half4v __attribute__((ext_vector_type(4)));
typedef float    floatx4 __attribute__((ext_vector_type(4)));

__device__ __forceinline__ void st_c(float* p, float v)    { *p = v; }
__device__ __forceinline__ void st_c(_Float16* p, float v) { *p = (_Float16)v; }

// async global->LDS, 16 B per lane, LDS dest = wave-uniform base + lane*16
__device__ __forceinline__ void gld16(const _Float16* g, _Float16* l) {
    __builtin_amdgcn_global_load_lds(
        (const __attribute__((address_space(1))) void*)g,
        (__attribute__((address_space(3))) void*)l, 16, 0, 0);
}

// ---------- 1. cast x (fp32 -> f16) ----------
__global__ void cast_x_kernel(const float* __restrict__ x, _Float16* __restrict__ xh) {
    int i = (blockIdx.x * 256 + threadIdx.x) * 4;
    float4 v = *(const float4*)(x + i);
    half4v h;
    h[0] = (_Float16)v.x; h[1] = (_Float16)v.y; h[2] = (_Float16)v.z; h[3] = (_Float16)v.w;
    *(half4v*)(xh + i) = h;
}

// ---------- 2a. transpose + cast (single source): out[C x R] = in[R x C]^T ----------
__global__ void transpose_cast(const float* __restrict__ in, _Float16* __restrict__ out,
                               int R, int C) {
    __shared__ float tile[32][33];
    int cb = blockIdx.x * 32, rb = blockIdx.y * 32;
    int tx = threadIdx.x, ty = threadIdx.y;    // 32 x 8
    #pragma unroll
    for (int j = 0; j < 32; j += 8)
        tile[ty + j][tx] = in[(size_t)(rb + ty + j) * C + (cb + tx)];
    __syncthreads();
    #pragma unroll
    for (int j = 0; j < 32; j += 8)
        out[(size_t)(cb + ty + j) * R + (rb + tx)] = (_Float16)tile[tx][ty + j];
}

// ---------- 2b. merged Wq/Wk/Wv transpose+cast into fused Wqkv[N=3072][K=2048] ----------
__global__ void transpose_cast_qkv(const float* __restrict__ Wq, const float* __restrict__ Wk,
                                   const float* __restrict__ Wv, _Float16* __restrict__ out) {
    __shared__ float tile[32][33];
    int cb = blockIdx.x * 32, rb = blockIdx.y * 32;   // cb: fused out-row 0..3071
    const float* src; int C, cl;
    if (cb < 2048)      { src = Wq; C = 2048; cl = cb; }
    else if (cb < 2560) { src = Wk; C = 512;  cl = cb - 2048; }
    else                { src = Wv; C = 512;  cl = cb - 2560; }
    int tx = threadIdx.x, ty = threadIdx.y;    // 32 x 8
    #pragma unroll
    for (int j = 0; j < 32; j += 8)
        tile[ty + j][tx] = src[(size_t)(rb + ty + j) * C + (cl + tx)];
    __syncthreads();
    #pragma unroll
    for (int j = 0; j < 32; j += 8)
        out[(size_t)(cb + ty + j) * EMB + (rb + tx)] = (_Float16)tile[tx][ty + j];
}

// ---------- 3. GEMM: C[M,N] = A[M,K] * Bt[N,K]^T  (f16 in, fp32 acc) ----------
// Best-measured structure (R2, 86us): gld16 direct staging + double-buffered
// LDS, one drain-barrier per K-step, prefetch issued a full compute-phase
// ahead. Schedule-level variants (single-buf, counted-vmcnt 3-buf, 256-tile
// coarse/fine phases) all measured equal or worse (R1/R3/R4/R5) -> this is
// the structural local optimum; remaining lever is locality, not schedule.
// NEW: T1 XCD-rectangle swizzle. Dispatch round-robins blocks across the 8
// XCD L2s, so by default every A-panel is re-fetched by all 8 XCDs (measured
// FETCH 76MB vs 29MB unique). Remap so each XCD owns a compile-time
// RXW x RYH rectangle of tiles: A-rows/B-cols reused within one L2.
template <typename CT, bool ROPE, int RXW, int RYH>
__global__ __launch_bounds__(256) void gemm_bt(const _Float16* __restrict__ A,
                                               const _Float16* __restrict__ Bt,
                                               CT* __restrict__ C,
                                               int M, int N, int K,
                                               const float* __restrict__ fc,
                                               const float* __restrict__ fs) {
    __shared__ _Float16 As[2][128 * 32];
    __shared__ _Float16 Bs[2][128 * 32];
    const int tid  = threadIdx.x;
    // XCD rectangle remap (grid = (2*RXW) x (4*RYH), both divisible by 8)
    const int bid = blockIdx.y * (2 * RXW) + blockIdx.x;
    const int xcd = bid & 7, loc = bid >> 3;
    const int bxi = (xcd & 1) * RXW + (loc % RXW);
    const int byi = (xcd >> 1) * RYH + (loc / RXW);
    const int bm  = byi * 128, bn = bxi * 128;
    const int lane = tid & 63, wid = tid >> 6;
    const int wr   = wid >> 1, wc = wid & 1;
    const int qd   = lane >> 4, m15 = lane & 15;

    // staging: wave wid covers rows [wid*16,+16) and [64+wid*16,+16) of each
    // 128x32 tile; lane l -> row wid*16+(l>>2), col (l&3)*8 (matches the
    // hardware's linear base+lane*16 LDS fill).
    const int srow = lane >> 2;
    const int scol = (lane & 3) * 8;
    const _Float16* Ag = A  + (size_t)(bm + wid * 16 + srow) * K + scol;
    const _Float16* Bg = Bt + (size_t)(bn + wid * 16 + srow) * K + scol;
    const size_t rowskip = (size_t)64 * K;
    const int woff = wid * 16 * 32;

    // prologue: stage tile 0 into buffer 0
    gld16(Ag,           &As[0][woff]);
    gld16(Ag + rowskip, &As[0][woff + 64 * 32]);
    gld16(Bg,           &Bs[0][woff]);
    gld16(Bg + rowskip, &Bs[0][woff + 64 * 32]);

    floatx4 acc[4][4] = {};
    const int nk = K >> 5;   // K/32 tiles

    for (int kt = 0; kt < nk; ++kt) {
        const int cur = kt & 1;
        __syncthreads();   // buf[cur] staged (vmcnt drained); prev reads of buf[cur^1] done
        if (kt + 1 < nk) { // stage tile kt+1 into the other buffer
            const int ko = (kt + 1) * 32;
            _Float16* aw = &As[cur ^ 1][woff];
            _Float16* bw = &Bs[cur ^ 1][woff];
            gld16(Ag + ko,           aw);
            gld16(Ag + rowskip + ko, aw + 64 * 32);
            gld16(Bg + ko,           bw);
            gld16(Bg + rowskip + ko, bw + 64 * 32);
        }
        const _Float16* AsR = &As[cur][(wr * 64 + m15) * 32 + qd * 8];
        const _Float16* BsR = &Bs[cur][(wc * 64 + m15) * 32 + qd * 8];
        half8 af[4], bf[4];
        #pragma unroll
        for (int i = 0; i < 4; i++) af[i] = *(const half8*)(AsR + i * 16 * 32);
        #pragma unroll
        for (int i = 0; i < 4; i++) bf[i] = *(const half8*)(BsR + i * 16 * 32);
        #pragma unroll
        for (int mi = 0; mi < 4; mi++)
            #pragma unroll
            for (int ni = 0; ni < 4; ni++)
                acc[mi][ni] = __builtin_amdgcn_mfma_f32_16x16x32_f16(af[mi], bf[ni], acc[mi][ni], 0, 0, 0);
    }

    #pragma unroll
    for (int mi = 0; mi < 4; mi++)
        #pragma unroll
        for (int ni = 0; ni < 4; ni++)
            #pragma unroll
            for (int r = 0; r < 4; r++) {
                int row = bm + wr * 64 + mi * 16 + qd * 4 + r;
                int col = bn + wc * 64 + ni * 16 + m15;
                float v = acc[mi][ni][r];
                if (ROPE && col < VOFF) {
                    int si = row & (SEQ - 1);
                    int fi = (col >> 1) & 63;
                    float c  = fc[si * 64 + fi];
                    float sn = fs[si * 64 + fi];
                    float other = __shfl_xor(v, 1, 64);
                    v = (m15 & 1) ? (v * c + other * sn) : (v * c - other * sn);
                }
                st_c(&C[(size_t)row * N + col], v);
            }
}

// ---------- 4b. V -> Vt[b][g][d][s]  (d rows 0..127) ----------
__global__ void transpose_v(const _Float16* __restrict__ qkv, _Float16* __restrict__ vt) {
    __shared__ _Float16 tile[32][33];
    int sb = blockIdx.x * 32, db = blockIdx.y * 32;
    int bg = blockIdx.z;
    int tx = threadIdx.x, ty = threadIdx.y;
    const _Float16* src = qkv + (size_t)(bg >> 2) * SEQ * NQKV + VOFF + (bg & 3) * HDIM;
    #pragma unroll
    for (int j = 0; j < 32; j += 8)
        tile[ty + j][tx] = src[(size_t)(sb + ty + j) * NQKV + db + tx];
    __syncthreads();
    _Float16* dst = vt + (size_t)bg * HDIM * SEQ;
    #pragma unroll
    for (int j = 0; j < 32; j += 8)
        dst[(size_t)(db + ty + j) * SEQ + sb + tx] = tile[tx][ty + j];
}

// ---------- 5. flash attention: 8 waves (4 heads x 2 row-halves), paired q-tiles ----------
// UNCHANGED this round (attribution + visibility: once qkv drops below it,
// attn's reps surface in top-5 and we get its real counters).
__global__ __launch_bounds__(512, 2) void flash_attn(const _Float16* __restrict__ qkv,
                                                     const _Float16* __restrict__ vt,
                                                     _Float16* __restrict__ ob) {
    const int bx   = blockIdx.x;   // 0..31
    const int g    = blockIdx.y;
    const int b    = blockIdx.z;
    const int tid  = threadIdx.x;
    const int lane = tid & 63, wid = tid >> 6;   // 8 waves
    const int h    = g * 4 + (wid & 3);
    const int su   = wid >> 2;
    const int qd   = lane >> 4, m15 = lane & 15;

    __shared__ _Float16 Ks[2][64 * 128];
    __shared__ _Float16 Vs[2][128 * 64];
    __shared__ _Float16 Ps[8][16 * 64];

    const _Float16* kg = qkv + (size_t)(b * SEQ) * NQKV + EMB + g * HDIM;
    const _Float16* vg = vt + (size_t)(b * GQA + g) * HDIM * SEQ;
    _Float16* pw = Ps[wid];

    const int kl = lane >> 4, kc16 = lane & 15;
    const int vl = lane >> 3, vc8  = lane & 7;
    const _Float16* kgp[2]; const _Float16* vgp[2];
    int ksoff[2], vsoff[2];
    #pragma unroll
    for (int j = 0; j < 2; j++) {
        int t = wid * 2 + j;
        int kr = t * 4 + kl;
        kgp[j] = kg + (size_t)kr * NQKV + ((kc16 ^ (kr & 15)) * 8);
        ksoff[j] = t * 512;
        int vr = t * 8 + vl;
        vgp[j] = vg + (size_t)vr * SEQ + ((vc8 ^ (vr & 7)) * 8);
        vsoff[j] = t * 512;
    }

    half8 ones;
    #pragma unroll
    for (int i = 0; i < 8; i++) ones[i] = (_Float16)1.0f;
    const _Float16 qsc = (_Float16)(0.08838834764831845f * 1.44269504088896341f);

    for (int ph = 0; ph < 2; ++ph) {
        const int sidx   = ph ? bx : 63 - bx;
        const int q0     = sidx * 32;
        const int ktLast = sidx >> 1;

        __syncthreads();
        #pragma unroll
        for (int j = 0; j < 2; j++) gld16(kgp[j], &Ks[0][ksoff[j]]);
        #pragma unroll
        for (int j = 0; j < 2; j++) gld16(vgp[j], &Vs[0][vsoff[j]]);

        half8 qf[4];
        {
            const _Float16* qb = qkv + (size_t)(b * SEQ + q0 + su * 16 + m15) * NQKV + h * HDIM + qd * 8;
            #pragma unroll
            for (int kc = 0; kc < 4; kc++) {
                half8 q = *(const half8*)(qb + kc * 32);
                #pragma unroll
                for (int i = 0; i < 8; i++) q[i] = (_Float16)(q[i] * qsc);
                qf[kc] = q;
            }
        }

        floatx4 o[9] = {};

        for (int kt = 0; kt <= ktLast; ++kt) {
            const int cur = kt & 1;
            __syncthreads();
            if (kt < ktLast) {
                const int nb = cur ^ 1;
                const size_t ko = (size_t)(kt + 1) * 64;
                #pragma unroll
                for (int j = 0; j < 2; j++) gld16(kgp[j] + ko * NQKV, &Ks[nb][ksoff[j]]);
                #pragma unroll
                for (int j = 0; j < 2; j++) gld16(vgp[j] + ko, &Vs[nb][vsoff[j]]);
            }
            const _Float16* ksb = Ks[cur];
            const _Float16* vsb = Vs[cur];

            floatx4 sa[4] = {};
            __builtin_amdgcn_s_setprio(1);
            #pragma unroll
            for (int nt = 0; nt < 4; ++nt) {
                const int kr = nt * 16 + m15;
                #pragma unroll
                for (int kc = 0; kc < 4; ++kc) {
                    half8 kf = *(const half8*)(&ksb[kr * 128 + (((kc * 4 + qd) ^ (kr & 15)) * 8)]);
                    sa[nt] = __builtin_amdgcn_mfma_f32_16x16x32_f16(qf[kc], kf, sa[nt], 0, 0, 0);
                }
            }
            __builtin_amdgcn_s_setprio(0);

            const bool diag = (kt == ktLast);
            const int  k0   = kt * 64;
            #pragma unroll
            for (int r = 0; r < 4; r++) {
                const int prow = qd * 4 + r;
                const int rowg = q0 + su * 16 + prow;
                #pragma unroll
                for (int nt = 0; nt < 4; nt++) {
                    float p = __builtin_exp2f(sa[nt][r]);
                    if (diag && (k0 + nt * 16 + m15 > rowg)) p = 0.f;
                    int chunk = (nt * 2 + (m15 >> 3)) ^ (prow & 7);
                    pw[prow * 64 + chunk * 8 + (m15 & 7)] = (_Float16)p;
                }
            }

            half8 pf[2];
            #pragma unroll
            for (int kc = 0; kc < 2; kc++)
                pf[kc] = *(const half8*)(&pw[m15 * 64 + (((kc * 4 + qd) ^ (m15 & 7)) * 8)]);

            __builtin_amdgcn_s_setprio(1);
            #pragma unroll
            for (int dt = 0; dt < 8; dt++) {
                const int vr = dt * 16 + m15;
                #pragma unroll
                for (int kc = 0; kc < 2; kc++) {
                    half8 vf = *(const half8*)(&vsb[vr * 64 + (((kc * 4 + qd) ^ (vr & 7)) * 8)]);
                    o[dt] = __builtin_amdgcn_mfma_f32_16x16x32_f16(pf[kc], vf, o[dt], 0, 0, 0);
                }
            }
            o[8] = __builtin_amdgcn_mfma_f32_16x16x32_f16(pf[0], ones, o[8], 0, 0, 0);
            o[8] = __builtin_amdgcn_mfma_f32_16x16x32_f16(pf[1], ones, o[8], 0, 0, 0);
            __builtin_amdgcn_s_setprio(0);
        }

        float linv[4];
        #pragma unroll
        for (int r = 0; r < 4; r++) linv[r] = 1.0f / o[8][r];
        _Float16* od = ob + (size_t)(b * SEQ + q0 + su * 16) * EMB + h * HDIM;
        #pragma unroll
        for (int dt = 0; dt < 8; dt++)
            #pragma unroll
            for (int r = 0; r < 4; r++)
                od[(size_t)(qd * 4 + r) * EMB + dt * 16 + m15] = (_Float16)(o[dt][r] * linv[r]);
    }
}

// ---------- launcher ----------
extern "C" void kernel_launch(void* const* d_in, const int* in_sizes, int n_in,
                              void* d_out, int out_size, void* d_ws, size_t ws_size,
                              hipStream_t stream) {
    (void)in_sizes; (void)n_in; (void)out_size; (void)ws_size;
    const float* x  = (const float*)d_in[0];
    const float* fc = (const float*)d_in[1];
    const float* fs = (const float*)d_in[2];
    const float* Wq = (const float*)d_in[3];
    const float* Wk = (const float*)d_in[4];
    const float* Wv = (const float*)d_in[5];
    const float* Wo = (const float*)d_in[6];
    float* out = (float*)d_out;

    // workspace layout (f16), 60 MB
    _Float16* Xb   = (_Float16*)d_ws;
    _Float16* Wqkv = Xb   + (size_t)MROWS * EMB;
    _Float16* WoT  = Wqkv + (size_t)NQKV * EMB;
    _Float16* C1   = WoT  + (size_t)EMB * EMB;
    _Float16* Vt   = Wqkv;                         // reuse (after QKV GEMM)
    _Float16* Ob   = Xb;                           // reuse (after QKV GEMM)

    dim3 tb(32, 8);
    cast_x_kernel<<<MROWS * EMB / 1024, 256, 0, stream>>>(x, Xb);
    transpose_cast_qkv<<<dim3(NQKV / 32, EMB / 32), tb, 0, stream>>>(Wq, Wk, Wv, Wqkv);
    transpose_cast<<<dim3(EMB / 32, EMB / 32), tb, 0, stream>>>(Wo, WoT, EMB, EMB);

    // QKV GEMM: grid (24,32)=768 blocks; XCD rects 12x8
    gemm_bt<_Float16, true, 12, 8><<<dim3(NQKV / 128, MROWS / 128), 256, 0, stream>>>(
        Xb, Wqkv, C1, MROWS, NQKV, EMB, fc, fs);
    transpose_v<<<dim3(SEQ / 32, HDIM / 32, BATCH * GQA), tb, 0, stream>>>(C1, Vt);
    flash_attn<<<dim3(32, GQA, BATCH), 512, 0, stream>>>(C1, Vt, Ob);
    // out-proj GEMM: grid (16,32)=512 blocks; XCD rects 8x8
    gemm_bt<float, false, 8, 8><<<dim3(EMB / 128, MROWS / 128), 256, 0, stream>>>(
        Ob, WoT, out, MROWS, EMB, EMB, nullptr, nullptr);
}